// Round 1
// 440.162 us; speedup vs baseline: 1.1004x; 1.1004x over previous
//
#include <hip/hip_runtime.h>
#include <hip/hip_bf16.h>
#include <math.h>

#define B_ 4
#define L_ 4096
#define D_ 1024
#define M_ (B_*L_)     // 16384
#define N_ 5120        // psi_re | psi_im | phi_re | phi_im | gate (1024 each)
#define K_ 1024
#define CHUNKS 128
#define LC 32          // L_ / CHUNKS
#define PL ((long)M_ * D_)   // plane elements = 16,777,216

// ws layout (bytes):
//   [0        , 33554432)  xb (bf16 x)              -- dead after GEMM
//   [33554432 , 44040192)  wb (bf16 W concat)       -- dead after GEMM
//   [44040192 , 211812352) raw5: 5 bf16 planes [g][M][D]
//       planes: 0=psi_re->H_re  1=psi_im->H_im  2=phi_re  3=phi_im  4=gate
//   overlay after GEMM (inside dead xb region):
//       E at [0, 4194304), carry at [4194304, 8388608), apow at [8388608, 8650752)
#define WS_NEEDED 211812352ull

typedef __attribute__((ext_vector_type(8))) short bf16x8;
typedef __attribute__((ext_vector_type(4))) float f32x4;

__device__ inline float b2f(short s) {
    unsigned u = ((unsigned)(unsigned short)s) << 16;
    float f; __builtin_memcpy(&f, &u, 4); return f;
}

// ---------------- K0: convert x and concat(W_psi, W_phi, W_gate) to bf16 (vectorized) ----
__device__ inline void cvt4(const float4* __restrict__ src, ushort* __restrict__ dst, long j) {
    float4 v = src[j];
    __hip_bfloat16 a = __float2bfloat16(v.x), b = __float2bfloat16(v.y),
                   c = __float2bfloat16(v.z), d = __float2bfloat16(v.w);
    ushort4 o = { *(ushort*)&a, *(ushort*)&b, *(ushort*)&c, *(ushort*)&d };
    *(ushort4*)(dst + j * 4) = o;
}

__global__ void convert_kernel(const float* __restrict__ x,
                               const float* __restrict__ Wpsi,
                               const float* __restrict__ Wphi,
                               const float* __restrict__ Wgate,
                               ushort* __restrict__ xb,
                               ushort* __restrict__ wb) {
    long i0 = (long)blockIdx.x * blockDim.x + threadIdx.x;
    long stride = (long)gridDim.x * blockDim.x;
    const long nx4 = ((long)M_ * K_) >> 2;           // 4,194,304
    for (long j = i0; j < nx4; j += stride) cvt4((const float4*)x, xb, j);
    const long nW14 = (2048L * 1024) >> 2, nW34 = (1024L * 1024) >> 2;
    for (long j = i0; j < nW14; j += stride) cvt4((const float4*)Wpsi, wb, j);
    for (long j = i0; j < nW14; j += stride) cvt4((const float4*)Wphi, wb + 2048L * 1024, j);
    for (long j = i0; j < nW34; j += stride) cvt4((const float4*)Wgate, wb + 4096L * 1024, j);
}

// ---------------- K1: bf16 MFMA GEMM — 256x256 tile, 8-phase counted-vmcnt schedule ----
// (T1 XCD swizzle + T2 st-swizzle LDS + T3/T4 8-phase counted vmcnt + T5 setprio)
// 8 waves (2m x 4n), per-wave C = 128x64. LDS 128KB: 2 dbuf x {Ah0,Ah1,Bh0,Bh1} 16KB slots.
// Stage ring during tile t: p0: t+1:Ah0  p1: t+1:Ah1  p2: t+2:Bh0  p3: t+2:Bh1
//   (B slots of cur dbuf dead after p1's ds_reads; A slots of cur dbuf only overwritten
//    at tile t+1 -> every LDS overwrite is barrier+lgkmcnt(0)-separated from its last reader)
// Tile-end wait vmcnt(4): last 4 loads = t+2:Bh0/Bh1 -> tile t+1 fully resident. Never 0
// until t = NT-2 (drain for the final tile).
#define BM2 256
#define BN2 256
#define BK2 64
#define NT  (K_ / BK2)        // 16
#define DBUF_BYTES 65536      // one K-tile: A(32KB) + B(32KB)

#define STAGE(gptr, brow, kt, slotoff)                                                       \
  do {                                                                                       \
    const __hip_bfloat16* g0_ = (gptr) + (long)((brow) + srow0) * K_ + (kt) * 64 + sgc0 * 8; \
    const __hip_bfloat16* g1_ = (gptr) + (long)((brow) + srow1) * K_ + (kt) * 64 + sgc1 * 8; \
    __builtin_amdgcn_global_load_lds((const __attribute__((address_space(1))) void*)g0_,     \
        (__attribute__((address_space(3))) void*)(smem + (slotoff) + ldst0), 16, 0, 0);      \
    __builtin_amdgcn_global_load_lds((const __attribute__((address_space(1))) void*)g1_,     \
        (__attribute__((address_space(3))) void*)(smem + (slotoff) + ldst1), 16, 0, 0);      \
  } while (0)

#define DSA(db, qm)                                                                 \
  _Pragma("unroll") for (int i_ = 0; i_ < 4; ++i_) {                                \
    aA[i_][0] = *(const bf16x8*)((db) + aoff + (qm) * 8192 + i_ * 2048 + ct0);      \
    aA[i_][1] = *(const bf16x8*)((db) + aoff + (qm) * 8192 + i_ * 2048 + ct1);      \
  }
#define DSB(db, qn, s)                                                              \
  _Pragma("unroll") for (int j_ = 0; j_ < 2; ++j_) {                                \
    bB[s][j_][0] = *(const bf16x8*)((db) + boff + (qn) * 4096 + j_ * 2048 + ct0);   \
    bB[s][j_][1] = *(const bf16x8*)((db) + boff + (qn) * 4096 + j_ * 2048 + ct1);   \
  }
#define MFMA16(qm, qn, s)                                                                         \
  _Pragma("unroll") for (int i_ = 0; i_ < 4; ++i_)                                                \
    _Pragma("unroll") for (int j_ = 0; j_ < 2; ++j_) {                                            \
      acc[(qm)*4+i_][(qn)*2+j_] = __builtin_amdgcn_mfma_f32_16x16x32_bf16(                        \
          aA[i_][0], bB[s][j_][0], acc[(qm)*4+i_][(qn)*2+j_], 0, 0, 0);                           \
      acc[(qm)*4+i_][(qn)*2+j_] = __builtin_amdgcn_mfma_f32_16x16x32_bf16(                        \
          aA[i_][1], bB[s][j_][1], acc[(qm)*4+i_][(qn)*2+j_], 0, 0, 0);                           \
    }
#define BARRIER __builtin_amdgcn_s_barrier()
#define LGKM0 do { asm volatile("s_waitcnt lgkmcnt(0)" ::: "memory");                             \
                   __builtin_amdgcn_sched_barrier(0); } while (0)

__global__ __launch_bounds__(512, 2)
void gemm_kernel(const __hip_bfloat16* __restrict__ xb,
                 const __hip_bfloat16* __restrict__ wb,
                 const float* __restrict__ b_psi,
                 const float* __restrict__ b_phi,
                 const float* __restrict__ b_gate,
                 __hip_bfloat16* __restrict__ raw5) {
    __shared__ __attribute__((aligned(16))) char smem[2 * DBUF_BYTES];   // 128 KB

    const int tid   = threadIdx.x;
    const int wid   = tid >> 6;
    const int lane  = tid & 63;
    const int row16 = lane & 15;
    const int quad  = lane >> 4;
    const int wm    = wid >> 2;   // 0..1 -> rows wm*128
    const int wn    = wid & 3;    // 0..3 -> cols wn*64

    // T1: XCD-aware block swizzle (nwg = 1280, %8 == 0 -> bijective)
    const int bid = blockIdx.y * 64 + blockIdx.x;
    const int swz = (bid & 7) * (1280 / 8) + (bid >> 3);
    const int m_blk = (swz & 63) * BM2;        // 64 m-tiles
    const int n_blk = (swz >> 6) * BN2;        // 20 n-tiles

    // staging constants (per-thread): seg = j*512 + tid -> (row, chunk), chunk swizzled
    const int srow0 = tid >> 3;
    const int srow1 = (512 + tid) >> 3;
    const int sch   = tid & 7;
    const int sgc0  = sch ^ (srow0 & 7);
    const int sgc1  = sch ^ (srow1 & 7);
    // LDS dest bases must be wave-uniform (HW adds lane*16)
    const int ldst0 = (wid * 64) * 16;
    const int ldst1 = (512 + wid * 64) * 16;

    // ds_read constants
    const int sw   = row16 & 7;
    const int aoff = wm * 16384 + row16 * 128;                                 // + qm*8192 + i*2048 + ct
    const int boff = 32768 + (wn >> 1) * 16384 + ((wn & 1) * 64 + row16) * 128; // + qn*4096 + j*2048 + ct
    const int ct0  = ((0 * 4 + quad) ^ sw) * 16;
    const int ct1  = ((1 * 4 + quad) ^ sw) * 16;

    bf16x8 aA[4][2];       // A frags for current qm window
    bf16x8 bB[2][2][2];    // [set(qn)][j][ks]
    f32x4  acc[8][4] = {};

    // ---- prologue: t0:{Ah0,Ah1,Bh0,Bh1}, t1:{Bh0,Bh1}  (12 loads), wait first 8 ----
    STAGE(xb, m_blk,       0, 0);
    STAGE(xb, m_blk + 128, 0, 16384);
    STAGE(wb, n_blk,       0, 32768);
    STAGE(wb, n_blk + 128, 0, 32768 + 16384);
    STAGE(wb, n_blk,       1, DBUF_BYTES + 32768);
    STAGE(wb, n_blk + 128, 1, DBUF_BYTES + 32768 + 16384);
    asm volatile("s_waitcnt vmcnt(4)" ::: "memory");
    BARRIER;

    for (int t = 0; t < NT; ++t) {
        char* db = smem + (t & 1) * DBUF_BYTES;
        const int nb = ((t + 1) & 1) * DBUF_BYTES;   // dbuf of tile t+1
        const int cb = (t & 1) * DBUF_BYTES;         // dbuf of tile t+2 (== cur)
        // ---- p0: read A(qm0)+B(qn0) [12], stage t+1:Ah0, mfma quad (0,0) ----
        DSA(db, 0); DSB(db, 0, 0);
        if (t + 1 < NT) STAGE(xb, m_blk, t + 1, nb);
        asm volatile("s_waitcnt lgkmcnt(8)" ::: "memory");
        BARRIER; LGKM0;
        __builtin_amdgcn_s_setprio(1); MFMA16(0, 0, 0); __builtin_amdgcn_s_setprio(0);
        BARRIER;
        // ---- p1: read B(qn1) [4], stage t+1:Ah1, mfma (0,1) ----
        DSB(db, 1, 1);
        if (t + 1 < NT) STAGE(xb, m_blk + 128, t + 1, nb + 16384);
        BARRIER; LGKM0;
        __builtin_amdgcn_s_setprio(1); MFMA16(0, 1, 1); __builtin_amdgcn_s_setprio(0);
        BARRIER;
        // ---- p2: read A(qm1) [8], stage t+2:Bh0 (B slots of cur dbuf now dead), mfma (1,1) ----
        DSA(db, 1);
        if (t + 2 < NT) STAGE(wb, n_blk, t + 2, cb + 32768);
        BARRIER; LGKM0;
        __builtin_amdgcn_s_setprio(1); MFMA16(1, 1, 1); __builtin_amdgcn_s_setprio(0);
        BARRIER;
        // ---- p3: stage t+2:Bh1, mfma (1,0), counted vmcnt, barrier ----
        if (t + 2 < NT) STAGE(wb, n_blk + 128, t + 2, cb + 32768 + 16384);
        BARRIER; LGKM0;
        __builtin_amdgcn_s_setprio(1); MFMA16(1, 0, 0); __builtin_amdgcn_s_setprio(0);
        if (t < NT - 2) { asm volatile("s_waitcnt vmcnt(4)" ::: "memory"); }
        else            { asm volatile("s_waitcnt vmcnt(0)" ::: "memory"); }
        BARRIER;
    }

    // ---- epilogue: bias + bf16 store into the 5 planes ----
#pragma unroll
    for (int mi = 0; mi < 8; ++mi) {
        const int mbase = m_blk + wm * 128 + (mi >> 2) * 64 + (mi & 3) * 16 + quad * 4;
#pragma unroll
        for (int nj = 0; nj < 4; ++nj) {
            int n = n_blk + wn * 64 + (nj >> 1) * 32 + (nj & 1) * 16 + row16;
            float bias = (n < 2048) ? b_psi[n] : (n < 4096) ? b_phi[n - 2048] : b_gate[n - 4096];
            int g = n >> 10, d = n & 1023;
            __hip_bfloat16* pl = raw5 + (long)g * PL;
#pragma unroll
            for (int r = 0; r < 4; ++r)
                pl[(long)(mbase + r) * D_ + d] = __float2bfloat16(acc[mi][nj][r] + bias);
        }
    }
}

// ---------------- K2: local scan (gate fused), H_local written in place over psi ------
__global__ __launch_bounds__(1024) void scan1_kernel(__hip_bfloat16* raw5,   // no restrict: in-place
                                                     const float* __restrict__ omega,
                                                     const float* __restrict__ log_gamma,
                                                     const float* __restrict__ dtp,
                                                     float2* __restrict__ E) {
    const int d = threadIdx.x;
    const int c = blockIdx.x;
    const int b = blockIdx.y;
    const float dt = fabsf(dtp[0]);
    const float decay = expf(-expf(log_gamma[d]) * dt);
    const float ang = omega[d] * dt;
    const float ar = decay * cosf(ang), ai = decay * sinf(ang);

    __hip_bfloat16* Pre = raw5;
    __hip_bfloat16* Pim = raw5 + PL;
    const __hip_bfloat16* Gt = raw5 + 4 * PL;
    long base = (long)(b * L_ + c * LC) * D_ + d;

    float hr = 0.f, hi = 0.f;
    for (int i = 0; i < LC; i++) {
        long idx = base + (long)i * D_;
        float sg = 1.f / (1.f + expf(-__bfloat162float(Gt[idx])));
        float ur = sg * __bfloat162float(Pre[idx]);
        float ui = sg * __bfloat162float(Pim[idx]);
        float nhr = ar * hr - ai * hi + ur;
        float nhi = ar * hi + ai * hr + ui;
        hr = nhr; hi = nhi;
        Pre[idx] = __float2bfloat16(hr);   // H_local overwrites psi (same thread, same idx)
        Pim[idx] = __float2bfloat16(hi);
    }
    E[((long)c * B_ + b) * D_ + d] = make_float2(hr, hi);
}

// ---------------- K3: Apow[i][d] = a_d^(i+1) ----------------
__global__ void apow_kernel(const float* __restrict__ omega,
                            const float* __restrict__ log_gamma,
                            const float* __restrict__ dtp,
                            float2* __restrict__ apow) {
    int t = blockIdx.x * blockDim.x + threadIdx.x;  // 0..32767
    int i = t >> 10, d = t & 1023;
    float dt = fabsf(dtp[0]);
    float e = expf(-expf(log_gamma[d]) * dt * (float)(i + 1));
    float ang = omega[d] * dt * (float)(i + 1);
    apow[t] = make_float2(e * cosf(ang), e * sinf(ang));
}

// ---------------- K4: carry via Kogge-Stone over chunks (one block per (b,d)) --------
__global__ __launch_bounds__(128) void carry_kernel(const float2* __restrict__ E,
                                                    const float* __restrict__ omega,
                                                    const float* __restrict__ log_gamma,
                                                    const float* __restrict__ dtp,
                                                    float2* __restrict__ carry) {
    __shared__ float2 sh[CHUNKS];
    const int c = threadIdx.x;
    const int bd = blockIdx.x;           // b*1024 + d
    const int b = bd >> 10, d = bd & 1023;
    const float dt = fabsf(dtp[0]);
    const float gd = expf(log_gamma[d]);
    const float wd = omega[d];

    float2 v = E[((long)c * B_ + b) * D_ + d];
    sh[c] = v;
    __syncthreads();
#pragma unroll
    for (int s = 1; s < CHUNKS; s <<= 1) {
        float2 prev;
        bool has = (c >= s);
        if (has) prev = sh[c - s];
        __syncthreads();
        if (has) {
            float t = dt * (float)LC * (float)s;
            float dec = expf(-gd * t);
            float ang = wd * t;
            float Ar = dec * cosf(ang), Ai = dec * sinf(ang);
            v.x += Ar * prev.x - Ai * prev.y;
            v.y += Ar * prev.y + Ai * prev.x;
            sh[c] = v;
        }
        __syncthreads();
    }
    float2 outv = (c == 0) ? make_float2(0.f, 0.f) : sh[c - 1];  // carry[c] = t_{c-1}
    carry[((long)c * B_ + b) * D_ + d] = outv;
}

// ---------------- K5: fixup + standardize + output (one wave per row, no barriers) ----
__global__ __launch_bounds__(256) void finish_kernel(const __hip_bfloat16* __restrict__ raw5,
                                                     const float2* __restrict__ carry,
                                                     const float2* __restrict__ apow,
                                                     float* __restrict__ out) {
    const int wv = threadIdx.x >> 6, lane = threadIdx.x & 63;
    const int r = blockIdx.x * 4 + wv;       // row 0..16383
    const int l = r & (L_ - 1);
    const int b = r >> 12;
    const int c = l >> 5, i = l & 31;
    const int d0 = lane * 16;
    const long base = (long)r * D_ + d0;

    const __hip_bfloat16* Hre = raw5;
    const __hip_bfloat16* Him = raw5 + PL;
    const __hip_bfloat16* Pre = raw5 + 2 * PL;
    const __hip_bfloat16* Pim = raw5 + 3 * PL;
    const float2* cr = carry + ((long)c * B_ + b) * D_ + d0;
    const float2* ap = apow + (long)i * D_ + d0;

    bf16x8 hre[2], him[2];
    hre[0] = *(const bf16x8*)(Hre + base);     hre[1] = *(const bf16x8*)(Hre + base + 8);
    him[0] = *(const bf16x8*)(Him + base);     him[1] = *(const bf16x8*)(Him + base + 8);

    float hr[16], hi[16];
    float s0 = 0.f, s1 = 0.f, s2 = 0.f, s3 = 0.f;
#pragma unroll
    for (int j = 0; j < 16; j++) {
        float2 cv = cr[j];
        float2 av = ap[j];
        float fr = av.x * cv.x - av.y * cv.y;
        float fi = av.x * cv.y + av.y * cv.x;
        float xr = b2f(hre[j >> 3][j & 7]) + fr;
        float xi = b2f(him[j >> 3][j & 7]) + fi;
        hr[j] = xr; hi[j] = xi;
        s0 += xr; s1 += xr * xr; s2 += xi; s3 += xi * xi;
    }
#pragma unroll
    for (int m = 1; m < 64; m <<= 1) {
        s0 += __shfl_xor(s0, m);
        s1 += __shfl_xor(s1, m);
        s2 += __shfl_xor(s2, m);
        s3 += __shfl_xor(s3, m);
    }
    float mean_r = s0 * (1.f / D_);
    float var_r  = s1 * (1.f / D_) - mean_r * mean_r;
    float mean_i = s2 * (1.f / D_);
    float var_i  = s3 * (1.f / D_) - mean_i * mean_i;
    float inv_r = 1.f / (sqrtf(fmaxf(var_r, 0.f)) + 1e-6f);
    float inv_i = 1.f / (sqrtf(fmaxf(var_i, 0.f)) + 1e-6f);

    bf16x8 pre[2], pim[2];
    pre[0] = *(const bf16x8*)(Pre + base);     pre[1] = *(const bf16x8*)(Pre + base + 8);
    pim[0] = *(const bf16x8*)(Pim + base);     pim[1] = *(const bf16x8*)(Pim + base + 8);

    float o[16];
#pragma unroll
    for (int j = 0; j < 16; j++)
        o[j] = (hr[j] - mean_r) * inv_r * b2f(pre[j >> 3][j & 7])
             + (hi[j] - mean_i) * inv_i * b2f(pim[j >> 3][j & 7]);
#pragma unroll
    for (int q = 0; q < 4; q++)
        *(float4*)(out + base + q * 4) = make_float4(o[q*4], o[q*4+1], o[q*4+2], o[q*4+3]);
}

// ---------------- launch ----------------
extern "C" void kernel_launch(void* const* d_in, const int* in_sizes, int n_in,
                              void* d_out, int out_size, void* d_ws, size_t ws_size,
                              hipStream_t stream) {
    (void)in_sizes; (void)n_in; (void)out_size;
    if (ws_size < WS_NEEDED) return;

    const float* x         = (const float*)d_in[0];
    const float* omega     = (const float*)d_in[1];
    const float* log_gamma = (const float*)d_in[2];
    const float* dt        = (const float*)d_in[3];
    const float* W_psi     = (const float*)d_in[4];
    const float* b_psi     = (const float*)d_in[5];
    const float* W_phi     = (const float*)d_in[6];
    const float* b_phi     = (const float*)d_in[7];
    const float* W_gate    = (const float*)d_in[8];
    const float* b_gate    = (const float*)d_in[9];

    char* ws = (char*)d_ws;
    __hip_bfloat16* xb   = (__hip_bfloat16*)(ws);
    __hip_bfloat16* wb   = (__hip_bfloat16*)(ws + 33554432);
    __hip_bfloat16* raw5 = (__hip_bfloat16*)(ws + 44040192);
    float2* E     = (float2*)(ws);                // overlays xb (dead after GEMM)
    float2* carry = (float2*)(ws + 4194304);
    float2* apow  = (float2*)(ws + 8388608);
    float* out = (float*)d_out;

    convert_kernel<<<2048, 256, 0, stream>>>(x, W_psi, W_phi, W_gate, (ushort*)xb, (ushort*)wb);
    gemm_kernel<<<dim3(M_ / BM2, N_ / BN2), 512, 0, stream>>>(xb, wb, b_psi, b_phi, b_gate, raw5);
    apow_kernel<<<128, 256, 0, stream>>>(omega, log_gamma, dt, apow);
    scan1_kernel<<<dim3(CHUNKS, B_), 1024, 0, stream>>>(raw5, omega, log_gamma, dt, E);
    carry_kernel<<<B_ * D_, 128, 0, stream>>>(E, omega, log_gamma, dt, carry);
    finish_kernel<<<M_ / 4, 256, 0, stream>>>(raw5, carry, apow, out);
}